// Round 19
// baseline (6487.885 us; speedup 1.0000x reference)
//
#include <hip/hip_runtime.h>

// B=128, T=512, I=256, H=512, O=256. GRU (r,z,n), 2 layers sharing one hidden
// state (quirk), y_t = h @ W_out^T + b_out.
//
// Round 19: EXACT round-15 kernel (best PASS, 5642 us; rounds 16/17/18
// perturbations all regressed) with one provably-safe micro: the y(t-1) MFMA
// (register-only, on hb) moves from after the flag store to BETWEEN the hlb
// stores and DRAIN_ALL — fills the store-ack window with compute, cannot
// lengthen the serial chain. Y stores stay off-chain after the flag.
//
// Structure: 4 machines x 32 rows; 32 blocks/machine (16 hidden cols each,
// weight slice in LDS); w0,w1 = phase A m-tiles, w2,w3 = phase B m-tiles;
// f32 carries in LDS; MALL sc0|sc1 exchange; monotonic flags; wave-decoupled
// sync (no __syncthreads in t-loop): 64 arrival lines/machine/phase, block
// s=0 gathers, 8 go-lines fan-out. Deadlock-free: unconditional monotonic
// stores, 128 blocks resident at 1 block/CU.

typedef short s16x8 __attribute__((ext_vector_type(8)));  // 8 bf16
typedef float f32x4 __attribute__((ext_vector_type(4)));
typedef unsigned short u16;
typedef unsigned int u32;

#define MFMA(a, b, c) __builtin_amdgcn_mfma_f32_16x16x32_bf16((a), (b), (c), 0, 0, 0)

static constexpr int NBLK = 128;       // 4 machines x 32 slices
static constexpr int LDS_WROWS = 112;  // 48 L0h + 64 L1 rows
static constexpr int LDS_STRIDE = 520; // 512 elems + 8 pad
static constexpr int LDS_BYTES = LDS_WROWS * LDS_STRIDE * 2 + 2 * 512 * 4;
// flag region (u32): FA[4][64][32] | FB[4][64][32] | GA[4][8][32] | GB[4][8][32]
static constexpr int OFF_FA = 0, OFF_FB = 8192, OFF_GA = 16384, OFF_GB = 17408;
static constexpr int FLAGS_U32 = 18432;

__device__ __forceinline__ u16 f2bf(float f) {
  unsigned u = __builtin_bit_cast(unsigned, f);
  u = u + 0x7fffu + ((u >> 16) & 1u);
  return (u16)(u >> 16);
}
__device__ __forceinline__ float sigm(float x) { return 1.f / (1.f + __expf(-x)); }
__device__ __forceinline__ float tanh_f(float x) { return 1.f - 2.f / (1.f + __expf(2.f * x)); }

// ---- MALL-direct helpers (rounds 5/9/12-15 proven) ----
__device__ __forceinline__ s16x8 scload16(const u16* p) {
  s16x8 v;
  asm volatile("global_load_dwordx4 %0, %1, off sc0 sc1" : "=v"(v) : "v"(p));
  return v;  // valid only after VWAIT0()
}
__device__ __forceinline__ void scstore_u16(u16* p, u16 v) {
  unsigned vv = v;
  asm volatile("global_store_short %0, %1, off sc0 sc1" :: "v"(p), "v"(vv) : "memory");
}
__device__ __forceinline__ u32 scload_u32(const u32* p) {
  u32 v;
  asm volatile("global_load_dword %0, %1, off sc0 sc1\n\ts_waitcnt vmcnt(0)"
               : "=v"(v) : "v"(p) : "memory");
  return v;
}
__device__ __forceinline__ void scstore_u32(u32* p, u32 v) {
  asm volatile("global_store_dword %0, %1, off sc0 sc1" :: "v"(p), "v"(v) : "memory");
}
#define VWAIT0()                                        \
  do {                                                  \
    asm volatile("s_waitcnt vmcnt(0)" ::: "memory");    \
    __builtin_amdgcn_sched_barrier(0);                  \
  } while (0)
#define DRAIN_ALL()                                              \
  do {                                                           \
    asm volatile("s_waitcnt vmcnt(0) lgkmcnt(0)" ::: "memory");  \
    __builtin_amdgcn_sched_barrier(0);                           \
  } while (0)

// Lead gather: 64 lanes watch 64 arrival lines (1 reader/line).
__device__ __forceinline__ void gather64(const u32* base, u32 val, int l) {
  for (;;) {
    u32 v = scload_u32(base + l * 32);
    if (__all(v >= val)) break;
    __builtin_amdgcn_s_sleep(2);
  }
}
// Worker poll: all lanes watch one go-line (uniform value).
__device__ __forceinline__ void pollgo(const u32* p, u32 val) {
  for (;;) {
    u32 v = scload_u32(p);
    if (v >= val) break;
    __builtin_amdgcn_s_sleep(4);
  }
}

// ---------------- weight prep + init (once per call) ----------------
__global__ void prep_kernel(const float* __restrict__ W_ih0, const float* __restrict__ W_hh0,
                            const float* __restrict__ W_ih1, const float* __restrict__ W_hh1,
                            const float* __restrict__ W_out, const float* __restrict__ h0,
                            u16* __restrict__ WL0, u16* __restrict__ WL1,
                            u16* __restrict__ WOB, u16* __restrict__ ring1,
                            u32* __restrict__ flags) {
  const int n0 = 1536 * 768, n1 = 2048 * 512, n2 = 256 * 512, n3 = 128 * 512;
  const int total = n0 + n1 + n2 + n3 + FLAGS_U32;
  for (int i = blockIdx.x * blockDim.x + threadIdx.x; i < total; i += gridDim.x * blockDim.x) {
    if (i < n0) {
      int row = i / 768, c = i % 768;
      float v = (c < 256) ? W_ih0[row * 256 + c] : W_hh0[row * 512 + (c - 256)];
      WL0[i] = f2bf(v);
    } else if (i < n0 + n1) {
      int k2 = i - n0;
      int row = k2 / 512, k = k2 % 512;
      int strip = row >> 9, j = row & 511;
      float v;
      if (strip == 0)      v = W_ih1[j * 512 + k] + W_hh1[j * 512 + k];
      else if (strip == 1) v = W_ih1[(512 + j) * 512 + k] + W_hh1[(512 + j) * 512 + k];
      else if (strip == 2) v = W_ih1[(1024 + j) * 512 + k];
      else                 v = W_hh1[(1024 + j) * 512 + k];
      WL1[k2] = f2bf(v);
    } else if (i < n0 + n1 + n2) {
      int k2 = i - n0 - n1;
      WOB[k2] = f2bf(W_out[k2]);
    } else if (i < n0 + n1 + n2 + n3) {
      int k2 = i - n0 - n1 - n2;
      ring1[k2] = f2bf(h0[k2]);     // ring[1] = h(-1) = h0
    } else {
      flags[i - n0 - n1 - n2 - n3] = 0u;
    }
  }
}

// ---------------- persistent GRU kernel (128 blocks x 256 thr) ---------------
__global__ __launch_bounds__(256) void gru_persist(
    const float* __restrict__ x, const float* __restrict__ h0,
    const float* __restrict__ b_ih0, const float* __restrict__ b_hh0,
    const float* __restrict__ b_ih1, const float* __restrict__ b_hh1,
    const float* __restrict__ b_out,
    const u16* __restrict__ WL0, const u16* __restrict__ WL1, const u16* __restrict__ WOB,
    u16* __restrict__ ring,      // [2][128][512] bf16
    u16* __restrict__ hlb,       // [128][512] bf16
    float* __restrict__ Y, u32* __restrict__ flags) {
  extern __shared__ u16 smem[];
  float* h_f32  = (float*)(smem + LDS_WROWS * LDS_STRIDE);  // [32][16]
  float* hl_f32 = h_f32 + 512;                              // [32][16]

  const int blk = blockIdx.x;
  const int m = blk >> 5;       // machine 0..3 (rows 32m..32m+31)
  const int s = blk & 31;       // hidden-col slice (cols s*16..s*16+15)
  const int w = threadIdx.x >> 6, l = threadIdx.x & 63;
  const int l15 = l & 15, l4 = l >> 4;

  // ---- init: weight slice -> LDS (identical to rounds 13-15) ----
  for (int idx = threadIdx.x; idx < LDS_WROWS * 512; idx += 256) {
    int row = idx >> 9, k = idx & 511;
    u16 v;
    if (row < 48) {
      int g = row >> 4, jj = row & 15;
      v = WL0[(size_t)(g * 512 + s * 16 + jj) * 768 + 256 + k];
    } else {
      int rr = row - 48, g = rr >> 4, jj = rr & 15;
      v = WL1[(size_t)(g * 512 + s * 16 + jj) * 512 + k];
    }
    smem[row * LDS_STRIDE + k] = v;
  }
  for (int idx = threadIdx.x; idx < 512; idx += 256) {
    int rr = idx >> 4, cc = idx & 15;
    h_f32[idx] = h0[(size_t)(32 * m + rr) * 512 + s * 16 + cc];
  }
  __syncthreads();

  const int jg = s * 16 + l15;
  const float br0 = b_ih0[jg] + b_hh0[jg];
  const float bz0 = b_ih0[512 + jg] + b_hh0[512 + jg];
  const float bni0 = b_ih0[1024 + jg], bnh0 = b_hh0[1024 + jg];
  const float br1 = b_ih1[jg] + b_hh1[jg];
  const float bz1 = b_ih1[512 + jg] + b_hh1[512 + jg];
  const float bni1 = b_ih1[1024 + jg], bnh1 = b_hh1[1024 + jg];

  const u16* wxr = WL0 + (size_t)jg * 768 + l4 * 8;
  const u16* wxz = WL0 + (size_t)(512 + jg) * 768 + l4 * 8;
  const u16* wxn = WL0 + (size_t)(1024 + jg) * 768 + l4 * 8;
  const u16* lr  = smem + (0 * 16 + l15) * LDS_STRIDE + l4 * 8;
  const u16* lz  = smem + (1 * 16 + l15) * LDS_STRIDE + l4 * 8;
  const u16* ln  = smem + (2 * 16 + l15) * LDS_STRIDE + l4 * 8;
  const u16* m10 = smem + (48 + 0 * 16 + l15) * LDS_STRIDE + l4 * 8;
  const u16* m11 = smem + (48 + 1 * 16 + l15) * LDS_STRIDE + l4 * 8;
  const u16* m12 = smem + (48 + 2 * 16 + l15) * LDS_STRIDE + l4 * 8;
  const u16* m13 = smem + (48 + 3 * 16 + l15) * LDS_STRIDE + l4 * 8;

  // machine's flag sub-regions
  u32* fA = flags + OFF_FA + m * 2048;   // 64 arrival lines (A)
  u32* fB = flags + OFF_FB + m * 2048;   // 64 arrival lines (B)
  u32* gA = flags + OFF_GA + m * 256;    // 8 go-lines (A done)
  u32* gB = flags + OFF_GB + m * 256;    // 8 go-lines (B done)

  if (w < 2) {
    // ================= A-waves (layer 0 + fused y) =================
    const int amt = w;
    const int arow = 32 * m + amt * 16 + l15;
    u32* myfA = fA + (s * 2 + amt) * 32;
    const u32* mygo = gB + (s & 7) * 32;
    const int yo = (s & 15) * 16 + l15;
    const float ybo = b_out[yo];
    const u16* ywv = WOB + (size_t)yo * 512 + l4 * 8;

    for (int t = 0; t < 512; ++t) {
      const u16* ringc = ring + (size_t)((t + 1) & 1) * 65536;  // h(t-1)

      // ---- wait: B(t-1) globally done ----
      if (t > 0) {
        if (s == 0) {
          gather64(fB, (u32)t, l);
          if (w == 0 && l < 8) scstore_u32(gB + l * 32, (u32)t);
        } else {
          pollgo(mygo, (u32)t);
        }
        __builtin_amdgcn_sched_barrier(0);
      }

      // ---- h-loads first; x-MFMA hides the RT ----
      s16x8 hb[16];
      const u16* hr = ringc + (size_t)arow * 512 + l4 * 8;
      #pragma unroll
      for (int kt = 0; kt < 16; ++kt) hb[kt] = scload16(hr + kt * 32);

      f32x4 aR = {0,0,0,0}, aZ = {0,0,0,0}, aNI = {0,0,0,0}, aNH = {0,0,0,0};
      const float* xr = x + ((size_t)arow * 512 + t) * 256 + l4 * 8;
      #pragma unroll
      for (int kt = 0; kt < 8; ++kt) {
        float4 u = *(const float4*)(xr + kt * 32);
        float4 v = *(const float4*)(xr + kt * 32 + 4);
        s16x8 a;
        a[0]=f2bf(u.x); a[1]=f2bf(u.y); a[2]=f2bf(u.z); a[3]=f2bf(u.w);
        a[4]=f2bf(v.x); a[5]=f2bf(v.y); a[6]=f2bf(v.z); a[7]=f2bf(v.w);
        aR  = MFMA(a, *(const s16x8*)(wxr + kt * 32), aR);
        aZ  = MFMA(a, *(const s16x8*)(wxz + kt * 32), aZ);
        aNI = MFMA(a, *(const s16x8*)(wxn + kt * 32), aNI);
      }
      VWAIT0();
      #pragma unroll
      for (int kt = 0; kt < 16; ++kt) {
        aR  = MFMA(hb[kt], *(const s16x8*)(lr + kt * 32), aR);
        aZ  = MFMA(hb[kt], *(const s16x8*)(lz + kt * 32), aZ);
        aNH = MFMA(hb[kt], *(const s16x8*)(ln + kt * 32), aNH);
      }

      // ---- L0 epilogue: carries + hlb stores ----
      #pragma unroll
      for (int j = 0; j < 4; ++j) {
        int rr = amt * 16 + l4 * 4 + j;
        float r = sigm(aR[j] + br0), z = sigm(aZ[j] + bz0);
        float n = tanh_f(aNI[j] + bni0 + r * (aNH[j] + bnh0));
        float h = (1.f - z) * n + z * h_f32[rr * 16 + l15];
        hl_f32[rr * 16 + l15] = h;
        scstore_u16(hlb + (size_t)(32 * m + rr) * 512 + jg, f2bf(h));
      }

      // ---- y(t-1) MFMA fills the store-ack window (register-only) ----
      f32x4 yacc = {0,0,0,0};
      if (s < 16 && t > 0) {
        #pragma unroll
        for (int kt = 0; kt < 16; ++kt)
          yacc = MFMA(hb[kt], *(const s16x8*)(ywv + kt * 32), yacc);
      }
      DRAIN_ALL();
      if (l == 0) scstore_u32(myfA, (u32)(t + 1));

      // ---- Y stores off-chain (hidden under phase B) ----
      if (s < 16 && t > 0) {
        #pragma unroll
        for (int j = 0; j < 4; ++j)
          Y[((size_t)(32 * m + amt * 16 + l4 * 4 + j) * 512 + (t - 1)) * 256 + yo]
              = yacc[j] + ybo;
      }
    }

    // ---- final y(511): wait B(511), then read ring[1] ----
    if (s == 0) {
      gather64(fB, 512u, l);
      if (w == 0 && l < 8) scstore_u32(gB + l * 32, 512u);
    } else {
      pollgo(mygo, 512u);
    }
    if (s < 16) {
      const u16* Hf = ring + 65536;
      s16x8 yb[16];
      const u16* ar = Hf + (size_t)arow * 512 + l4 * 8;
      #pragma unroll
      for (int kt = 0; kt < 16; ++kt) yb[kt] = scload16(ar + kt * 32);
      VWAIT0();
      f32x4 acc = {0,0,0,0};
      #pragma unroll
      for (int kt = 0; kt < 16; ++kt)
        acc = MFMA(yb[kt], *(const s16x8*)(ywv + kt * 32), acc);
      #pragma unroll
      for (int j = 0; j < 4; ++j)
        Y[((size_t)(32 * m + amt * 16 + l4 * 4 + j) * 512 + 511) * 256 + yo]
            = acc[j] + ybo;
    }
  } else {
    // ================= B-waves (layer 1) =================
    const int bmt = w - 2;
    const int brow = 32 * m + bmt * 16 + l15;
    u32* myfB = fB + (s * 2 + bmt) * 32;
    const u32* mygo = gA + (s & 7) * 32;

    for (int t = 0; t < 512; ++t) {
      u16* ringn = ring + (size_t)(t & 1) * 65536;  // h(t) dest

      // ---- wait: A(t) globally done ----
      if (s == 0) {
        gather64(fA, (u32)(t + 1), l);
        if (w == 2 && l < 8) scstore_u32(gA + l * 32, (u32)(t + 1));
      } else {
        pollgo(mygo, (u32)(t + 1));
      }
      __builtin_amdgcn_sched_barrier(0);

      // ---- load h_l0, MFMA ----
      s16x8 pb[16];
      const u16* ar = hlb + (size_t)brow * 512 + l4 * 8;
      #pragma unroll
      for (int kt = 0; kt < 16; ++kt) pb[kt] = scload16(ar + kt * 32);
      VWAIT0();
      f32x4 cR = {0,0,0,0}, cZ = {0,0,0,0}, cNI = {0,0,0,0}, cNH = {0,0,0,0};
      #pragma unroll
      for (int kt = 0; kt < 16; ++kt) {
        cR  = MFMA(pb[kt], *(const s16x8*)(m10 + kt * 32), cR);
        cZ  = MFMA(pb[kt], *(const s16x8*)(m11 + kt * 32), cZ);
        cNI = MFMA(pb[kt], *(const s16x8*)(m12 + kt * 32), cNI);
        cNH = MFMA(pb[kt], *(const s16x8*)(m13 + kt * 32), cNH);
      }
      #pragma unroll
      for (int j = 0; j < 4; ++j) {
        int rr = bmt * 16 + l4 * 4 + j;
        float r = sigm(cR[j] + br1), z = sigm(cZ[j] + bz1);
        float n = tanh_f(cNI[j] + bni1 + r * (cNH[j] + bnh1));
        float h = (1.f - z) * n + z * hl_f32[rr * 16 + l15];
        h_f32[rr * 16 + l15] = h;
        scstore_u16(ringn + (size_t)(32 * m + rr) * 512 + jg, f2bf(h));
      }
      DRAIN_ALL();
      if (l == 0) scstore_u32(myfB, (u32)(t + 1));
    }
  }
}

extern "C" void kernel_launch(void* const* d_in, const int* in_sizes, int n_in,
                              void* d_out, int out_size, void* d_ws, size_t ws_size,
                              hipStream_t stream) {
  const float* x     = (const float*)d_in[0];
  const float* h0    = (const float*)d_in[1];
  const float* W_ih0 = (const float*)d_in[2];
  const float* W_hh0 = (const float*)d_in[3];
  const float* b_ih0 = (const float*)d_in[4];
  const float* b_hh0 = (const float*)d_in[5];
  const float* W_ih1 = (const float*)d_in[6];
  const float* W_hh1 = (const float*)d_in[7];
  const float* b_ih1 = (const float*)d_in[8];
  const float* b_hh1 = (const float*)d_in[9];
  const float* W_out = (const float*)d_in[10];
  const float* b_out = (const float*)d_in[11];
  float* Y = (float*)d_out;

  // ws carve: flags (72 KB) | weights | ring[2] | hlb  (~5.0 MiB)
  u32* flags = (u32*)d_ws;
  u16* WL0  = (u16*)(flags + FLAGS_U32);
  u16* WL1  = WL0 + 1536 * 768;
  u16* WOB  = WL1 + 2048 * 512;
  u16* ring = WOB + 256 * 512;
  u16* hlb  = ring + 2 * 65536;

  (void)hipFuncSetAttribute((const void*)gru_persist,
                            hipFuncAttributeMaxDynamicSharedMemorySize, LDS_BYTES);

  prep_kernel<<<dim3(1024), dim3(256), 0, stream>>>(W_ih0, W_hh0, W_ih1, W_hh1,
                                                    W_out, h0, WL0, WL1, WOB,
                                                    ring + 65536, flags);
  gru_persist<<<dim3(NBLK), dim3(256), LDS_BYTES, stream>>>(
      x, h0, b_ih0, b_hh0, b_ih1, b_hh1, b_out, WL0, WL1, WOB,
      ring, hlb, Y, flags);
}

// Round 20
// 5635.375 us; speedup vs baseline: 1.1513x; 1.1513x over previous
//
#include <hip/hip_runtime.h>

// B=128, T=512, I=256, H=512, O=256. GRU (r,z,n), 2 layers sharing one hidden
// state (quirk), y_t = h @ W_out^T + b_out.
//
// Round 20: byte-for-byte RESTORE of the round-15 kernel — the best PASS
// (5,642 us). Six perturbations around it (r16 tile-split, r17 mailbox
// fan-out, r18 x-pipeline + transposed stores, r19 y-before-drain) ALL
// regressed with understood mechanisms; round 15 is a genuine local optimum.
// Structure: 4 machines x 32 rows; 32 blocks/machine (16 hidden cols each,
// weight slice in LDS); w0,w1 = phase A m-tiles, w2,w3 = phase B m-tiles;
// f32 carries in LDS; MALL sc0|sc1 exchange; monotonic flags; wave-decoupled
// sync (no __syncthreads in t-loop): 64 arrival lines/machine/phase, block
// s=0 gathers, 8 go-lines fan-out; y(t-1) deferred AFTER the flag store
// (the y-MFMA is a dependent chain — it must not delay the flag).

typedef short s16x8 __attribute__((ext_vector_type(8)));  // 8 bf16
typedef float f32x4 __attribute__((ext_vector_type(4)));
typedef unsigned short u16;
typedef unsigned int u32;

#define MFMA(a, b, c) __builtin_amdgcn_mfma_f32_16x16x32_bf16((a), (b), (c), 0, 0, 0)

static constexpr int NBLK = 128;       // 4 machines x 32 slices
static constexpr int LDS_WROWS = 112;  // 48 L0h + 64 L1 rows
static constexpr int LDS_STRIDE = 520; // 512 elems + 8 pad
static constexpr int LDS_BYTES = LDS_WROWS * LDS_STRIDE * 2 + 2 * 512 * 4;
// flag region (u32): FA[4][64][32] | FB[4][64][32] | GA[4][8][32] | GB[4][8][32]
static constexpr int OFF_FA = 0, OFF_FB = 8192, OFF_GA = 16384, OFF_GB = 17408;
static constexpr int FLAGS_U32 = 18432;

__device__ __forceinline__ u16 f2bf(float f) {
  unsigned u = __builtin_bit_cast(unsigned, f);
  u = u + 0x7fffu + ((u >> 16) & 1u);
  return (u16)(u >> 16);
}
__device__ __forceinline__ float sigm(float x) { return 1.f / (1.f + __expf(-x)); }
__device__ __forceinline__ float tanh_f(float x) { return 1.f - 2.f / (1.f + __expf(2.f * x)); }

// ---- MALL-direct helpers (rounds 5/9/12-15 proven) ----
__device__ __forceinline__ s16x8 scload16(const u16* p) {
  s16x8 v;
  asm volatile("global_load_dwordx4 %0, %1, off sc0 sc1" : "=v"(v) : "v"(p));
  return v;  // valid only after VWAIT0()
}
__device__ __forceinline__ void scstore_u16(u16* p, u16 v) {
  unsigned vv = v;
  asm volatile("global_store_short %0, %1, off sc0 sc1" :: "v"(p), "v"(vv) : "memory");
}
__device__ __forceinline__ u32 scload_u32(const u32* p) {
  u32 v;
  asm volatile("global_load_dword %0, %1, off sc0 sc1\n\ts_waitcnt vmcnt(0)"
               : "=v"(v) : "v"(p) : "memory");
  return v;
}
__device__ __forceinline__ void scstore_u32(u32* p, u32 v) {
  asm volatile("global_store_dword %0, %1, off sc0 sc1" :: "v"(p), "v"(v) : "memory");
}
#define VWAIT0()                                        \
  do {                                                  \
    asm volatile("s_waitcnt vmcnt(0)" ::: "memory");    \
    __builtin_amdgcn_sched_barrier(0);                  \
  } while (0)
#define DRAIN_ALL()                                              \
  do {                                                           \
    asm volatile("s_waitcnt vmcnt(0) lgkmcnt(0)" ::: "memory");  \
    __builtin_amdgcn_sched_barrier(0);                           \
  } while (0)

// Lead gather: 64 lanes watch 64 arrival lines (1 reader/line).
__device__ __forceinline__ void gather64(const u32* base, u32 val, int l) {
  for (;;) {
    u32 v = scload_u32(base + l * 32);
    if (__all(v >= val)) break;
    __builtin_amdgcn_s_sleep(2);
  }
}
// Worker poll: all lanes watch one go-line (uniform value).
__device__ __forceinline__ void pollgo(const u32* p, u32 val) {
  for (;;) {
    u32 v = scload_u32(p);
    if (v >= val) break;
    __builtin_amdgcn_s_sleep(4);
  }
}

// ---------------- weight prep + init (once per call) ----------------
__global__ void prep_kernel(const float* __restrict__ W_ih0, const float* __restrict__ W_hh0,
                            const float* __restrict__ W_ih1, const float* __restrict__ W_hh1,
                            const float* __restrict__ W_out, const float* __restrict__ h0,
                            u16* __restrict__ WL0, u16* __restrict__ WL1,
                            u16* __restrict__ WOB, u16* __restrict__ ring1,
                            u32* __restrict__ flags) {
  const int n0 = 1536 * 768, n1 = 2048 * 512, n2 = 256 * 512, n3 = 128 * 512;
  const int total = n0 + n1 + n2 + n3 + FLAGS_U32;
  for (int i = blockIdx.x * blockDim.x + threadIdx.x; i < total; i += gridDim.x * blockDim.x) {
    if (i < n0) {
      int row = i / 768, c = i % 768;
      float v = (c < 256) ? W_ih0[row * 256 + c] : W_hh0[row * 512 + (c - 256)];
      WL0[i] = f2bf(v);
    } else if (i < n0 + n1) {
      int k2 = i - n0;
      int row = k2 / 512, k = k2 % 512;
      int strip = row >> 9, j = row & 511;
      float v;
      if (strip == 0)      v = W_ih1[j * 512 + k] + W_hh1[j * 512 + k];
      else if (strip == 1) v = W_ih1[(512 + j) * 512 + k] + W_hh1[(512 + j) * 512 + k];
      else if (strip == 2) v = W_ih1[(1024 + j) * 512 + k];
      else                 v = W_hh1[(1024 + j) * 512 + k];
      WL1[k2] = f2bf(v);
    } else if (i < n0 + n1 + n2) {
      int k2 = i - n0 - n1;
      WOB[k2] = f2bf(W_out[k2]);
    } else if (i < n0 + n1 + n2 + n3) {
      int k2 = i - n0 - n1 - n2;
      ring1[k2] = f2bf(h0[k2]);     // ring[1] = h(-1) = h0
    } else {
      flags[i - n0 - n1 - n2 - n3] = 0u;
    }
  }
}

// ---------------- persistent GRU kernel (128 blocks x 256 thr) ---------------
__global__ __launch_bounds__(256) void gru_persist(
    const float* __restrict__ x, const float* __restrict__ h0,
    const float* __restrict__ b_ih0, const float* __restrict__ b_hh0,
    const float* __restrict__ b_ih1, const float* __restrict__ b_hh1,
    const float* __restrict__ b_out,
    const u16* __restrict__ WL0, const u16* __restrict__ WL1, const u16* __restrict__ WOB,
    u16* __restrict__ ring,      // [2][128][512] bf16
    u16* __restrict__ hlb,       // [128][512] bf16
    float* __restrict__ Y, u32* __restrict__ flags) {
  extern __shared__ u16 smem[];
  float* h_f32  = (float*)(smem + LDS_WROWS * LDS_STRIDE);  // [32][16]
  float* hl_f32 = h_f32 + 512;                              // [32][16]

  const int blk = blockIdx.x;
  const int m = blk >> 5;       // machine 0..3 (rows 32m..32m+31)
  const int s = blk & 31;       // hidden-col slice (cols s*16..s*16+15)
  const int w = threadIdx.x >> 6, l = threadIdx.x & 63;
  const int l15 = l & 15, l4 = l >> 4;

  // ---- init: weight slice -> LDS (identical to rounds 13-15) ----
  for (int idx = threadIdx.x; idx < LDS_WROWS * 512; idx += 256) {
    int row = idx >> 9, k = idx & 511;
    u16 v;
    if (row < 48) {
      int g = row >> 4, jj = row & 15;
      v = WL0[(size_t)(g * 512 + s * 16 + jj) * 768 + 256 + k];
    } else {
      int rr = row - 48, g = rr >> 4, jj = rr & 15;
      v = WL1[(size_t)(g * 512 + s * 16 + jj) * 512 + k];
    }
    smem[row * LDS_STRIDE + k] = v;
  }
  for (int idx = threadIdx.x; idx < 512; idx += 256) {
    int rr = idx >> 4, cc = idx & 15;
    h_f32[idx] = h0[(size_t)(32 * m + rr) * 512 + s * 16 + cc];
  }
  __syncthreads();

  const int jg = s * 16 + l15;
  const float br0 = b_ih0[jg] + b_hh0[jg];
  const float bz0 = b_ih0[512 + jg] + b_hh0[512 + jg];
  const float bni0 = b_ih0[1024 + jg], bnh0 = b_hh0[1024 + jg];
  const float br1 = b_ih1[jg] + b_hh1[jg];
  const float bz1 = b_ih1[512 + jg] + b_hh1[512 + jg];
  const float bni1 = b_ih1[1024 + jg], bnh1 = b_hh1[1024 + jg];

  const u16* wxr = WL0 + (size_t)jg * 768 + l4 * 8;
  const u16* wxz = WL0 + (size_t)(512 + jg) * 768 + l4 * 8;
  const u16* wxn = WL0 + (size_t)(1024 + jg) * 768 + l4 * 8;
  const u16* lr  = smem + (0 * 16 + l15) * LDS_STRIDE + l4 * 8;
  const u16* lz  = smem + (1 * 16 + l15) * LDS_STRIDE + l4 * 8;
  const u16* ln  = smem + (2 * 16 + l15) * LDS_STRIDE + l4 * 8;
  const u16* m10 = smem + (48 + 0 * 16 + l15) * LDS_STRIDE + l4 * 8;
  const u16* m11 = smem + (48 + 1 * 16 + l15) * LDS_STRIDE + l4 * 8;
  const u16* m12 = smem + (48 + 2 * 16 + l15) * LDS_STRIDE + l4 * 8;
  const u16* m13 = smem + (48 + 3 * 16 + l15) * LDS_STRIDE + l4 * 8;

  // machine's flag sub-regions
  u32* fA = flags + OFF_FA + m * 2048;   // 64 arrival lines (A)
  u32* fB = flags + OFF_FB + m * 2048;   // 64 arrival lines (B)
  u32* gA = flags + OFF_GA + m * 256;    // 8 go-lines (A done)
  u32* gB = flags + OFF_GB + m * 256;    // 8 go-lines (B done)

  if (w < 2) {
    // ================= A-waves (layer 0 + fused y) =================
    const int amt = w;
    const int arow = 32 * m + amt * 16 + l15;
    u32* myfA = fA + (s * 2 + amt) * 32;
    const u32* mygo = gB + (s & 7) * 32;
    const int yo = (s & 15) * 16 + l15;
    const float ybo = b_out[yo];
    const u16* ywv = WOB + (size_t)yo * 512 + l4 * 8;

    for (int t = 0; t < 512; ++t) {
      const u16* ringc = ring + (size_t)((t + 1) & 1) * 65536;  // h(t-1)

      // ---- wait: B(t-1) globally done ----
      if (t > 0) {
        if (s == 0) {
          gather64(fB, (u32)t, l);
          if (w == 0 && l < 8) scstore_u32(gB + l * 32, (u32)t);
        } else {
          pollgo(mygo, (u32)t);
        }
        __builtin_amdgcn_sched_barrier(0);
      }

      // ---- h-loads first; x-MFMA hides the RT ----
      s16x8 hb[16];
      const u16* hr = ringc + (size_t)arow * 512 + l4 * 8;
      #pragma unroll
      for (int kt = 0; kt < 16; ++kt) hb[kt] = scload16(hr + kt * 32);

      f32x4 aR = {0,0,0,0}, aZ = {0,0,0,0}, aNI = {0,0,0,0}, aNH = {0,0,0,0};
      const float* xr = x + ((size_t)arow * 512 + t) * 256 + l4 * 8;
      #pragma unroll
      for (int kt = 0; kt < 8; ++kt) {
        float4 u = *(const float4*)(xr + kt * 32);
        float4 v = *(const float4*)(xr + kt * 32 + 4);
        s16x8 a;
        a[0]=f2bf(u.x); a[1]=f2bf(u.y); a[2]=f2bf(u.z); a[3]=f2bf(u.w);
        a[4]=f2bf(v.x); a[5]=f2bf(v.y); a[6]=f2bf(v.z); a[7]=f2bf(v.w);
        aR  = MFMA(a, *(const s16x8*)(wxr + kt * 32), aR);
        aZ  = MFMA(a, *(const s16x8*)(wxz + kt * 32), aZ);
        aNI = MFMA(a, *(const s16x8*)(wxn + kt * 32), aNI);
      }
      VWAIT0();
      #pragma unroll
      for (int kt = 0; kt < 16; ++kt) {
        aR  = MFMA(hb[kt], *(const s16x8*)(lr + kt * 32), aR);
        aZ  = MFMA(hb[kt], *(const s16x8*)(lz + kt * 32), aZ);
        aNH = MFMA(hb[kt], *(const s16x8*)(ln + kt * 32), aNH);
      }

      // ---- L0 epilogue: carries + hlb stores ----
      #pragma unroll
      for (int j = 0; j < 4; ++j) {
        int rr = amt * 16 + l4 * 4 + j;
        float r = sigm(aR[j] + br0), z = sigm(aZ[j] + bz0);
        float n = tanh_f(aNI[j] + bni0 + r * (aNH[j] + bnh0));
        float h = (1.f - z) * n + z * h_f32[rr * 16 + l15];
        hl_f32[rr * 16 + l15] = h;
        scstore_u16(hlb + (size_t)(32 * m + rr) * 512 + jg, f2bf(h));
      }
      DRAIN_ALL();
      if (l == 0) scstore_u32(myfA, (u32)(t + 1));

      // ---- deferred y(t-1) from hb registers (hidden under phase B) ----
      if (s < 16 && t > 0) {
        f32x4 acc = {0,0,0,0};
        #pragma unroll
        for (int kt = 0; kt < 16; ++kt)
          acc = MFMA(hb[kt], *(const s16x8*)(ywv + kt * 32), acc);
        #pragma unroll
        for (int j = 0; j < 4; ++j)
          Y[((size_t)(32 * m + amt * 16 + l4 * 4 + j) * 512 + (t - 1)) * 256 + yo]
              = acc[j] + ybo;
      }
    }

    // ---- final y(511): wait B(511), then read ring[1] ----
    if (s == 0) {
      gather64(fB, 512u, l);
      if (w == 0 && l < 8) scstore_u32(gB + l * 32, 512u);
    } else {
      pollgo(mygo, 512u);
    }
    if (s < 16) {
      const u16* Hf = ring + 65536;
      s16x8 yb[16];
      const u16* ar = Hf + (size_t)arow * 512 + l4 * 8;
      #pragma unroll
      for (int kt = 0; kt < 16; ++kt) yb[kt] = scload16(ar + kt * 32);
      VWAIT0();
      f32x4 acc = {0,0,0,0};
      #pragma unroll
      for (int kt = 0; kt < 16; ++kt)
        acc = MFMA(yb[kt], *(const s16x8*)(ywv + kt * 32), acc);
      #pragma unroll
      for (int j = 0; j < 4; ++j)
        Y[((size_t)(32 * m + amt * 16 + l4 * 4 + j) * 512 + 511) * 256 + yo]
            = acc[j] + ybo;
    }
  } else {
    // ================= B-waves (layer 1) =================
    const int bmt = w - 2;
    const int brow = 32 * m + bmt * 16 + l15;
    u32* myfB = fB + (s * 2 + bmt) * 32;
    const u32* mygo = gA + (s & 7) * 32;

    for (int t = 0; t < 512; ++t) {
      u16* ringn = ring + (size_t)(t & 1) * 65536;  // h(t) dest

      // ---- wait: A(t) globally done ----
      if (s == 0) {
        gather64(fA, (u32)(t + 1), l);
        if (w == 2 && l < 8) scstore_u32(gA + l * 32, (u32)(t + 1));
      } else {
        pollgo(mygo, (u32)(t + 1));
      }
      __builtin_amdgcn_sched_barrier(0);

      // ---- load h_l0, MFMA ----
      s16x8 pb[16];
      const u16* ar = hlb + (size_t)brow * 512 + l4 * 8;
      #pragma unroll
      for (int kt = 0; kt < 16; ++kt) pb[kt] = scload16(ar + kt * 32);
      VWAIT0();
      f32x4 cR = {0,0,0,0}, cZ = {0,0,0,0}, cNI = {0,0,0,0}, cNH = {0,0,0,0};
      #pragma unroll
      for (int kt = 0; kt < 16; ++kt) {
        cR  = MFMA(pb[kt], *(const s16x8*)(m10 + kt * 32), cR);
        cZ  = MFMA(pb[kt], *(const s16x8*)(m11 + kt * 32), cZ);
        cNI = MFMA(pb[kt], *(const s16x8*)(m12 + kt * 32), cNI);
        cNH = MFMA(pb[kt], *(const s16x8*)(m13 + kt * 32), cNH);
      }
      #pragma unroll
      for (int j = 0; j < 4; ++j) {
        int rr = bmt * 16 + l4 * 4 + j;
        float r = sigm(cR[j] + br1), z = sigm(cZ[j] + bz1);
        float n = tanh_f(cNI[j] + bni1 + r * (cNH[j] + bnh1));
        float h = (1.f - z) * n + z * hl_f32[rr * 16 + l15];
        h_f32[rr * 16 + l15] = h;
        scstore_u16(ringn + (size_t)(32 * m + rr) * 512 + jg, f2bf(h));
      }
      DRAIN_ALL();
      if (l == 0) scstore_u32(myfB, (u32)(t + 1));
    }
  }
}

extern "C" void kernel_launch(void* const* d_in, const int* in_sizes, int n_in,
                              void* d_out, int out_size, void* d_ws, size_t ws_size,
                              hipStream_t stream) {
  const float* x     = (const float*)d_in[0];
  const float* h0    = (const float*)d_in[1];
  const float* W_ih0 = (const float*)d_in[2];
  const float* W_hh0 = (const float*)d_in[3];
  const float* b_ih0 = (const float*)d_in[4];
  const float* b_hh0 = (const float*)d_in[5];
  const float* W_ih1 = (const float*)d_in[6];
  const float* W_hh1 = (const float*)d_in[7];
  const float* b_ih1 = (const float*)d_in[8];
  const float* b_hh1 = (const float*)d_in[9];
  const float* W_out = (const float*)d_in[10];
  const float* b_out = (const float*)d_in[11];
  float* Y = (float*)d_out;

  // ws carve: flags (72 KB) | weights | ring[2] | hlb  (~5.0 MiB)
  u32* flags = (u32*)d_ws;
  u16* WL0  = (u16*)(flags + FLAGS_U32);
  u16* WL1  = WL0 + 1536 * 768;
  u16* WOB  = WL1 + 2048 * 512;
  u16* ring = WOB + 256 * 512;
  u16* hlb  = ring + 2 * 65536;

  (void)hipFuncSetAttribute((const void*)gru_persist,
                            hipFuncAttributeMaxDynamicSharedMemorySize, LDS_BYTES);

  prep_kernel<<<dim3(1024), dim3(256), 0, stream>>>(W_ih0, W_hh0, W_ih1, W_hh1,
                                                    W_out, h0, WL0, WL1, WOB,
                                                    ring + 65536, flags);
  gru_persist<<<dim3(NBLK), dim3(256), LDS_BYTES, stream>>>(
      x, h0, b_ih0, b_hh0, b_ih1, b_hh1, b_out, WL0, WL1, WOB,
      ring, hlb, Y, flags);
}